// Round 2
// baseline (1217.205 us; speedup 1.0000x reference)
//
#include <hip/hip_runtime.h>
#include <hip/hip_fp16.h>
#include <math.h>

#define BLK 256

// ---------------------------------------------------------------------------
// GCNPolicyNetwork: 3-layer improved-GCN + masked softmax + mean-pool value.
// R1 (this session): fuse k_place + k_agg1 + k_agg2 + k_agg3 + k_final into
// one persistent kernel with manual device-scope grid barriers.
//   - __launch_bounds__(256,4) => 4 blocks/CU guaranteed => 1024 co-resident
//     blocks >= 782 launched => spin barrier cannot deadlock.
//   - barrier: atomicAdd arrive + __threadfence (agent wb/inv) both sides —
//     same cache semantics a kernel boundary already pays; saves 4 dispatch
//     gaps + per-kernel setup, and offs/degi/dinv are loaded once into regs
//     for all three agg phases.
// k_bin stays separate (1024-thread geometry, 76% occupancy on its own).
// ---------------------------------------------------------------------------

#define BSH 8                    // 256 nodes per bucket
#define NB 512                   // bucket-array size (nbuck=391 <= 512)
#define CAP 10240                // packed[] capacity per bucket (mean ~8184)
#define SCAP 12288               // srcs[] capacity per bucket (CAP + 8*256 pad)
#define EB 8192                  // edges per binning block
#define BINTH 1024               // k_bin block size

// ---- fp16 payload helpers ----
__device__ inline float4 load_h4(const __half* base, int node, int sub) {
    const uint2* p = reinterpret_cast<const uint2*>(base + ((size_t)node << 4)) + sub;
    uint2 u = *p;
    union { unsigned u; __half2 h; } a, b;
    a.u = u.x; b.u = u.y;
    float2 fa = __half22float2(a.h), fb = __half22float2(b.h);
    return make_float4(fa.x, fa.y, fb.x, fb.y);
}

__device__ inline void store_h4(__half* base, int node, int sub, float4 v) {
    union { unsigned u; __half2 h; } a, b;
    a.h = __floats2half2_rn(v.x, v.y);
    b.h = __floats2half2_rn(v.z, v.w);
    uint2 u; u.x = a.u; u.y = b.u;
    *(reinterpret_cast<uint2*>(base + ((size_t)node << 4)) + sub) = u;
}

// xs payload: half4 (dinv*x0, dinv*x1, dinv*x2, 0) = 8 B per node
__device__ inline float3 load_xs(const __half* xs, int node) {
    uint2 u = *reinterpret_cast<const uint2*>(xs + ((size_t)node << 2));
    union { unsigned u; __half2 h; } a, b;
    a.u = u.x; b.u = u.y;
    float2 fa = __half22float2(a.h), fb = __half22float2(b.h);
    return make_float3(fa.x, fa.y, fb.x);
}

// device-scope grid barrier: all gridDim.x blocks arrive; monotonic counter.
__device__ __forceinline__ void gbar(int* bar, int target) {
    __syncthreads();
    if (threadIdx.x == 0) {
        __threadfence();   // release: drain + writeback L2 (agent scope)
        __hip_atomic_fetch_add(bar, 1, __ATOMIC_RELEASE, __HIP_MEMORY_SCOPE_AGENT);
        while (__hip_atomic_load(bar, __ATOMIC_ACQUIRE, __HIP_MEMORY_SCOPE_AGENT) < target)
            __builtin_amdgcn_s_sleep(1);
        __threadfence();   // acquire: invalidate L1/L2 so remote writes visible
    }
    __syncthreads();
}

// zero gcur[NB] + scal[18] + bar
__global__ void k_init(int* __restrict__ gcur, float* __restrict__ scal,
                       int* __restrict__ bar) {
    int t = threadIdx.x;
    gcur[t] = 0;
    if (t < 18) scal[t] = 0.f;
    if (t == 0) *bar = 0;
}

// LDS multisplit of edges into 256-node buckets; reserve directly in the
// fixed-capacity packed[] layout (bucket b owns [b*CAP, b*CAP+cnt)).
__global__ void __launch_bounds__(BINTH) k_bin(const int* __restrict__ row,
                                               const int* __restrict__ col,
                                               int* __restrict__ gcur,
                                               int* __restrict__ packed, int E) {
    __shared__ int stage[EB];
    __shared__ unsigned short sbuk[EB];
    __shared__ int hist[NB];
    __shared__ int lscan[NB];
    __shared__ int cur[NB];
    __shared__ int gbase[NB];
    int tid = threadIdx.x;
    int base = blockIdx.x * EB;
    int cnt = min(EB, E - base);

    if (tid < NB) hist[tid] = 0;
    __syncthreads();
    for (int j = tid; j < cnt; j += BINTH) {
        int c = __builtin_nontemporal_load(col + base + j);
        atomicAdd(&hist[c >> BSH], 1);
    }
    __syncthreads();
    if (tid < NB) lscan[tid] = hist[tid];
    __syncthreads();
    for (int d = 1; d < NB; d <<= 1) {
        int t = (tid < NB && tid >= d) ? lscan[tid - d] : 0;
        __syncthreads();
        if (tid < NB && tid >= d) lscan[tid] += t;
        __syncthreads();
    }
    if (tid < NB) {
        int ex = lscan[tid] - hist[tid];
        lscan[tid] = ex;
        cur[tid] = ex;
    }
    __syncthreads();
    for (int j = tid; j < cnt; j += BINTH) {
        int c = __builtin_nontemporal_load(col + base + j);
        int r = __builtin_nontemporal_load(row + base + j);
        int b = c >> BSH;
        int p = atomicAdd(&cur[b], 1);
        stage[p] = (r << BSH) | (c & ((1 << BSH) - 1));
        sbuk[p] = (unsigned short)b;
    }
    __syncthreads();
    if (tid < NB && hist[tid] > 0)
        gbase[tid] = tid * CAP + atomicAdd(&gcur[tid], hist[tid]);
    __syncthreads();
    for (int j = tid; j < cnt; j += BINTH) {
        int b = sbuk[j];
        int pos = gbase[b] + (j - lscan[b]);
        packed[pos] = stage[j];
    }
}

// ---------------------------------------------------------------------------
// Fused persistent kernel: place | agg1 | agg2 | agg3 | final with grid
// barriers between phases. 782 blocks x 256 threads, 4 blocks/CU guaranteed.
// ---------------------------------------------------------------------------
__global__ void __launch_bounds__(BLK, 4) k_fused(
        const int* __restrict__ packed, const int* __restrict__ bcnt,
        const float* __restrict__ x,
        int* __restrict__ degi, int* __restrict__ offs,
        float* __restrict__ dinv, __half* __restrict__ xs,
        int* __restrict__ srcs,
        const float* __restrict__ b1, const float* __restrict__ W1,
        const float* __restrict__ W2, __half* __restrict__ hwsB,
        const float* __restrict__ b2, const float* __restrict__ W3,
        float* __restrict__ hws3, float* __restrict__ pool,
        const float* __restrict__ b3, const int* __restrict__ choices,
        float* __restrict__ cbuf, float* __restrict__ bmax,
        float* __restrict__ bsum,
        const float* __restrict__ fcw, const float* __restrict__ fcb,
        float* __restrict__ out,
        int* __restrict__ bar, int n, int nbuck, int nblkF) {
    __shared__ __align__(16) char smem[10240];
    int tid = threadIdx.x;
    int bx = blockIdx.x;
    int NVB = gridDim.x;

    // ================= phase 0: place (vb < nbuck) =================
    if (bx < nbuck) {
        int* cnt  = (int*)smem;
        int* lcur = cnt + 256;
        int* ssum = lcur + 256;
        int nb0 = bx << BSH;
        cnt[tid] = 0;
        __syncthreads();
        int ecnt = bcnt[bx];
        const int* pk = packed + (size_t)bx * CAP;
        for (int j = tid; j < ecnt; j += BLK)
            atomicAdd(&cnt[pk[j] & 255], 1);
        __syncthreads();
        int c = cnt[tid];
        int pl = (c + 7) & ~7;                 // padded length (x8)
        ssum[tid] = pl;
        __syncthreads();
        for (int d = 1; d < 256; d <<= 1) {
            int t = (tid >= d) ? ssum[tid - d] : 0;
            __syncthreads();
            if (tid >= d) ssum[tid] += t;
            __syncthreads();
        }
        int A = bx * SCAP + (ssum[tid] - pl);  // absolute aligned base for node
        lcur[tid] = A;
        int valid = min(n - nb0, 256);
        int i = nb0 + tid;
        if (tid < valid) {
            degi[i] = pl;
            offs[i] = A;
            float di = rsqrtf((float)c + 2.0f);
            dinv[i] = di;
            float x0 = x[i * 3 + 0], x1 = x[i * 3 + 1], x2 = x[i * 3 + 2];
            union { unsigned u; __half2 h; } a2, b2u;
            a2.h = __floats2half2_rn(di * x0, di * x1);
            b2u.h = __floats2half2_rn(di * x2, 0.f);
            uint2 u; u.x = a2.u; u.y = b2u.u;
            *reinterpret_cast<uint2*>(xs + ((size_t)i << 2)) = u;
            for (int k = c; k < pl; k++) srcs[A + k] = n;   // dummy pads
        }
        if (bx == 0 && tid == 0) {             // zero the dummy xs payload
            uint2 z; z.x = 0u; z.y = 0u;
            *reinterpret_cast<uint2*>(xs + ((size_t)n << 2)) = z;
        }
        __syncthreads();
        for (int j = tid; j < ecnt; j += BLK) {
            int v = pk[j];
            int slot = atomicAdd(&lcur[v & 255], 1);
            srcs[slot] = v >> BSH;
        }
    }
    gbar(bar, NVB);

    // ---- per-node metadata, loaded once for all three agg phases ----
    int nl = tid >> 2, sub = tid & 3;
    int iA = bx * 128 + nl;
    int iB = iA + 64;
    bool actA = (iA < n), actB = (iB < n);
    int AA = actA ? offs[iA] : 0;
    int AB = actB ? offs[iB] : 0;
    int plA = actA ? degi[iA] : 0;
    int plB = actB ? degi[iB] : 0;
    float diA = actA ? dinv[iA] : 0.f;
    float diB = actB ? dinv[iB] : 0.f;
    int plM = max(plA, plB);

    // ================= phase 1: agg1 =================
    {
        float* w1 = (float*)smem;              // 48
        float* w2 = w1 + 48;                   // 256
        float* bb = w2 + 256;                  // 16
        float (*hbuf)[17] = (float(*)[17])(bb + 16);   // 128 x 17
        w2[tid] = W2[tid];
        if (tid < 48) w1[tid] = W1[tid];
        if (tid < 16) bb[tid] = b1[tid];
        if (bx == 0 && tid < 8)                // zero the dummy hwsB payload
            reinterpret_cast<unsigned*>(hwsB + ((size_t)n << 4))[tid] = 0u;
        __syncthreads();
        float axA = 0.f, ayA = 0.f, azA = 0.f;
        float axB = 0.f, ayB = 0.f, azB = 0.f;
        for (int j = 4 * sub; j < plM; j += 16) {
            int ja = min(j, max(plA - 4, 0));
            int jb = min(j, max(plB - 4, 0));
            int4 sa = *reinterpret_cast<const int4*>(srcs + AA + ja);
            int4 sb = *reinterpret_cast<const int4*>(srcs + AB + jb);
            if (j >= plA) sa = make_int4(n, n, n, n);
            if (j >= plB) sb = make_int4(n, n, n, n);
            float3 qa0 = load_xs(xs, sa.x);
            float3 qa1 = load_xs(xs, sa.y);
            float3 qa2 = load_xs(xs, sa.z);
            float3 qa3 = load_xs(xs, sa.w);
            float3 qb0 = load_xs(xs, sb.x);
            float3 qb1 = load_xs(xs, sb.y);
            float3 qb2 = load_xs(xs, sb.z);
            float3 qb3 = load_xs(xs, sb.w);
            axA += qa0.x + qa1.x + qa2.x + qa3.x;
            ayA += qa0.y + qa1.y + qa2.y + qa3.y;
            azA += qa0.z + qa1.z + qa2.z + qa3.z;
            axB += qb0.x + qb1.x + qb2.x + qb3.x;
            ayB += qb0.y + qb1.y + qb2.y + qb3.y;
            azB += qb0.z + qb1.z + qb2.z + qb3.z;
        }
        axA += __shfl_xor(axA, 1); ayA += __shfl_xor(ayA, 1); azA += __shfl_xor(azA, 1);
        axA += __shfl_xor(axA, 2); ayA += __shfl_xor(ayA, 2); azA += __shfl_xor(azA, 2);
        axB += __shfl_xor(axB, 1); ayB += __shfl_xor(ayB, 1); azB += __shfl_xor(azB, 1);
        axB += __shfl_xor(axB, 2); ayB += __shfl_xor(ayB, 2); azB += __shfl_xor(azB, 2);
        if (actA) {
            float3 s = load_xs(xs, iA);
            float ax = axA + 2.f * s.x, ay = ayA + 2.f * s.y, az = azA + 2.f * s.z;
#pragma unroll
            for (int k = 0; k < 4; k++) {
                int f = sub * 4 + k;
                float hv = diA * (ax * w1[f] + ay * w1[16 + f] + az * w1[32 + f]) + bb[f];
                hbuf[nl][f] = fmaxf(hv, 0.f);
            }
        }
        if (actB) {
            float3 s = load_xs(xs, iB);
            float ax = axB + 2.f * s.x, ay = ayB + 2.f * s.y, az = azB + 2.f * s.z;
#pragma unroll
            for (int k = 0; k < 4; k++) {
                int f = sub * 4 + k;
                float hv = diB * (ax * w1[f] + ay * w1[16 + f] + az * w1[32 + f]) + bb[f];
                hbuf[64 + nl][f] = fmaxf(hv, 0.f);
            }
        }
        __syncthreads();
        if (actA) {
            const float* hn = hbuf[nl];
            float s0 = 0.f, s1 = 0.f, s2 = 0.f, s3 = 0.f;
#pragma unroll
            for (int f = 0; f < 16; f++) {
                float hv = hn[f];
                const float4 wq = *(const float4*)&w2[f * 16 + sub * 4];
                s0 += hv * wq.x; s1 += hv * wq.y; s2 += hv * wq.z; s3 += hv * wq.w;
            }
            store_h4(hwsB, iA, sub, make_float4(diA * s0, diA * s1, diA * s2, diA * s3));
        }
        if (actB) {
            const float* hn = hbuf[64 + nl];
            float s0 = 0.f, s1 = 0.f, s2 = 0.f, s3 = 0.f;
#pragma unroll
            for (int f = 0; f < 16; f++) {
                float hv = hn[f];
                const float4 wq = *(const float4*)&w2[f * 16 + sub * 4];
                s0 += hv * wq.x; s1 += hv * wq.y; s2 += hv * wq.z; s3 += hv * wq.w;
            }
            store_h4(hwsB, iB, sub, make_float4(diB * s0, diB * s1, diB * s2, diB * s3));
        }
    }
    gbar(bar, NVB * 2);

    // ================= phase 2: agg2 (+pool, +layer-3 transform) =================
    {
        float* w3 = (float*)smem;              // 16
        float* bb = w3 + 16;                   // 16
        float* lp = bb + 16;                   // 16
        if (tid < 16) { w3[tid] = W3[tid]; bb[tid] = b2[tid]; lp[tid] = 0.f; }
        if (bx == 0 && tid == 0) hws3[n] = 0.f;   // zero dummy hws3
        __syncthreads();
        float4 z4 = make_float4(0.f, 0.f, 0.f, 0.f);
        float4 sA = actA ? load_h4(hwsB, iA, sub) : z4;
        float4 sB = actB ? load_h4(hwsB, iB, sub) : z4;
        float4 accA = make_float4(2.f * sA.x, 2.f * sA.y, 2.f * sA.z, 2.f * sA.w);
        float4 accB = make_float4(2.f * sB.x, 2.f * sB.y, 2.f * sB.z, 2.f * sB.w);
        float4 a1A = z4, a1B = z4;
        for (int j = 0; j < plM; j += 8) {
            int ja = min(j, max(plA - 8, 0));
            int jb = min(j, max(plB - 8, 0));
            int4 sa0 = *reinterpret_cast<const int4*>(srcs + AA + ja);
            int4 sa1 = *reinterpret_cast<const int4*>(srcs + AA + ja + 4);
            int4 sb0 = *reinterpret_cast<const int4*>(srcs + AB + jb);
            int4 sb1 = *reinterpret_cast<const int4*>(srcs + AB + jb + 4);
            if (j >= plA) { sa0 = make_int4(n, n, n, n); sa1 = sa0; }
            if (j >= plB) { sb0 = make_int4(n, n, n, n); sb1 = sb0; }
            float4 qa0 = load_h4(hwsB, sa0.x, sub);
            float4 qa1 = load_h4(hwsB, sa0.y, sub);
            float4 qa2 = load_h4(hwsB, sa0.z, sub);
            float4 qa3 = load_h4(hwsB, sa0.w, sub);
            float4 qa4 = load_h4(hwsB, sa1.x, sub);
            float4 qa5 = load_h4(hwsB, sa1.y, sub);
            float4 qa6 = load_h4(hwsB, sa1.z, sub);
            float4 qa7 = load_h4(hwsB, sa1.w, sub);
            float4 qb0 = load_h4(hwsB, sb0.x, sub);
            float4 qb1 = load_h4(hwsB, sb0.y, sub);
            float4 qb2 = load_h4(hwsB, sb0.z, sub);
            float4 qb3 = load_h4(hwsB, sb0.w, sub);
            float4 qb4 = load_h4(hwsB, sb1.x, sub);
            float4 qb5 = load_h4(hwsB, sb1.y, sub);
            float4 qb6 = load_h4(hwsB, sb1.z, sub);
            float4 qb7 = load_h4(hwsB, sb1.w, sub);
            accA.x += qa0.x + qa2.x + qa4.x + qa6.x;
            accA.y += qa0.y + qa2.y + qa4.y + qa6.y;
            accA.z += qa0.z + qa2.z + qa4.z + qa6.z;
            accA.w += qa0.w + qa2.w + qa4.w + qa6.w;
            a1A.x += qa1.x + qa3.x + qa5.x + qa7.x;
            a1A.y += qa1.y + qa3.y + qa5.y + qa7.y;
            a1A.z += qa1.z + qa3.z + qa5.z + qa7.z;
            a1A.w += qa1.w + qa3.w + qa5.w + qa7.w;
            accB.x += qb0.x + qb2.x + qb4.x + qb6.x;
            accB.y += qb0.y + qb2.y + qb4.y + qb6.y;
            accB.z += qb0.z + qb2.z + qb4.z + qb6.z;
            accB.w += qb0.w + qb2.w + qb4.w + qb6.w;
            a1B.x += qb1.x + qb3.x + qb5.x + qb7.x;
            a1B.y += qb1.y + qb3.y + qb5.y + qb7.y;
            a1B.z += qb1.z + qb3.z + qb5.z + qb7.z;
            a1B.w += qb1.w + qb3.w + qb5.w + qb7.w;
        }
        accA.x += a1A.x; accA.y += a1A.y; accA.z += a1A.z; accA.w += a1A.w;
        accB.x += a1B.x; accB.y += a1B.y; accB.z += a1B.z; accB.w += a1B.w;
        float4 hA = z4, hB = z4;
        if (actA) {
            hA.x = fmaxf(diA * accA.x + bb[sub * 4 + 0], 0.f);
            hA.y = fmaxf(diA * accA.y + bb[sub * 4 + 1], 0.f);
            hA.z = fmaxf(diA * accA.z + bb[sub * 4 + 2], 0.f);
            hA.w = fmaxf(diA * accA.w + bb[sub * 4 + 3], 0.f);
        }
        if (actB) {
            hB.x = fmaxf(diB * accB.x + bb[sub * 4 + 0], 0.f);
            hB.y = fmaxf(diB * accB.y + bb[sub * 4 + 1], 0.f);
            hB.z = fmaxf(diB * accB.z + bb[sub * 4 + 2], 0.f);
            hB.w = fmaxf(diB * accB.w + bb[sub * 4 + 3], 0.f);
        }
        float pA = hA.x * w3[sub * 4 + 0] + hA.y * w3[sub * 4 + 1]
                 + hA.z * w3[sub * 4 + 2] + hA.w * w3[sub * 4 + 3];
        float pB = hB.x * w3[sub * 4 + 0] + hB.y * w3[sub * 4 + 1]
                 + hB.z * w3[sub * 4 + 2] + hB.w * w3[sub * 4 + 3];
        pA += __shfl_xor(pA, 1); pA += __shfl_xor(pA, 2);
        pB += __shfl_xor(pB, 1); pB += __shfl_xor(pB, 2);
        if (sub == 0) {
            if (actA) hws3[iA] = diA * pA;
            if (actB) hws3[iB] = diB * pB;
        }
        float4 hp = make_float4(hA.x + hB.x, hA.y + hB.y, hA.z + hB.z, hA.w + hB.w);
#pragma unroll
        for (int m = 4; m < 64; m <<= 1) {
            hp.x += __shfl_xor(hp.x, m);
            hp.y += __shfl_xor(hp.y, m);
            hp.z += __shfl_xor(hp.z, m);
            hp.w += __shfl_xor(hp.w, m);
        }
        if ((tid & 63) < 4) {
            atomicAdd(&lp[sub * 4 + 0], hp.x);
            atomicAdd(&lp[sub * 4 + 1], hp.y);
            atomicAdd(&lp[sub * 4 + 2], hp.z);
            atomicAdd(&lp[sub * 4 + 3], hp.w);
        }
        __syncthreads();
        if (tid < 16) atomicAdd(&pool[tid], lp[tid]);
    }
    gbar(bar, NVB * 3);

    // ================= phase 3: agg3 =================
    {
        float* red = (float*)smem;             // 256
        float sA0 = 0.f, sA1 = 0.f, sB0 = 0.f, sB1 = 0.f;
        for (int j = 8 * sub; j < plM; j += 32) {
            int ja = min(j, max(plA - 8, 0));
            int jb = min(j, max(plB - 8, 0));
            int4 sa0 = *reinterpret_cast<const int4*>(srcs + AA + ja);
            int4 sa1 = *reinterpret_cast<const int4*>(srcs + AA + ja + 4);
            int4 sb0 = *reinterpret_cast<const int4*>(srcs + AB + jb);
            int4 sb1 = *reinterpret_cast<const int4*>(srcs + AB + jb + 4);
            if (j >= plA) { sa0 = make_int4(n, n, n, n); sa1 = sa0; }
            if (j >= plB) { sb0 = make_int4(n, n, n, n); sb1 = sb0; }
            sA0 += hws3[sa0.x] + hws3[sa0.z] + hws3[sa1.x] + hws3[sa1.z];
            sA1 += hws3[sa0.y] + hws3[sa0.w] + hws3[sa1.y] + hws3[sa1.w];
            sB0 += hws3[sb0.x] + hws3[sb0.z] + hws3[sb1.x] + hws3[sb1.z];
            sB1 += hws3[sb0.y] + hws3[sb0.w] + hws3[sb1.y] + hws3[sb1.w];
        }
        float sA = sA0 + sA1, sB = sB0 + sB1;
        sA += __shfl_xor(sA, 1); sA += __shfl_xor(sA, 2);
        sB += __shfl_xor(sB, 1); sB += __shfl_xor(sB, 2);
        float lA = -INFINITY, lB = -INFINITY;
        if (sub == 0) {
            if (actA) {
                float c = diA * (sA + 2.f * hws3[iA]) + b3[0];
                cbuf[iA] = c;
                if (choices[iA] != 0) lA = c;
            }
            if (actB) {
                float c = diB * (sB + 2.f * hws3[iB]) + b3[0];
                cbuf[iB] = c;
                if (choices[iB] != 0) lB = c;
            }
        }
        red[tid] = fmaxf(lA, lB);
        __syncthreads();
        for (int d = BLK / 2; d > 0; d >>= 1) {
            if (tid < d) red[tid] = fmaxf(red[tid], red[tid + d]);
            __syncthreads();
        }
        float bm = red[0];
        __syncthreads();
        float es = 0.f;
        if (lA > -INFINITY) es += expf(lA - bm);
        if (lB > -INFINITY) es += expf(lB - bm);
        red[tid] = es;
        __syncthreads();
        for (int d = BLK / 2; d > 0; d >>= 1) {
            if (tid < d) red[tid] += red[tid + d];
            __syncthreads();
        }
        if (tid == 0) { bmax[bx] = bm; bsum[bx] = red[0]; }
    }
    gbar(bar, NVB * 4);

    // ================= phase 4: final (vb < nblkF) =================
    if (bx < nblkF) {
        float* red = (float*)smem;             // 256
        float* MS  = red + 256;                // 2
        float m = -INFINITY;
        for (int i = tid; i < NVB; i += BLK) m = fmaxf(m, bmax[i]);
        red[tid] = m;
        __syncthreads();
        for (int d = BLK / 2; d > 0; d >>= 1) {
            if (tid < d) red[tid] = fmaxf(red[tid], red[tid + d]);
            __syncthreads();
        }
        float M = red[0];
        __syncthreads();
        float s = 0.f;
        for (int i = tid; i < NVB; i += BLK) {
            float bm = bmax[i];
            if (bm > -INFINITY) s += bsum[i] * expf(bm - M);
        }
        red[tid] = s;
        __syncthreads();
        for (int d = BLK / 2; d > 0; d >>= 1) {
            if (tid < d) red[tid] += red[tid + d];
            __syncthreads();
        }
        if (tid == 0) { MS[0] = M; MS[1] = red[0]; }
        __syncthreads();
        float Mv = MS[0], Sv = MS[1];
        int i = bx * BLK + tid;
        if (i < n) {
            float p = 0.0f;
            if (choices[i] != 0) p = expf(cbuf[i] - Mv) / Sv;
            out[i] = p;
        }
        if (bx == 0 && tid == 0) {
            float invn = 1.0f / (float)n;
            float v = 0.0f;
#pragma unroll
            for (int f = 0; f < 16; f++) v += (pool[f] * invn) * fcw[f];
            out[n] = v + fcb[0];
        }
    }
}

extern "C" void kernel_launch(void* const* d_in, const int* in_sizes, int n_in,
                              void* d_out, int out_size, void* d_ws, size_t ws_size,
                              hipStream_t stream) {
    const float* x       = (const float*)d_in[0];
    const int*   ei      = (const int*)d_in[1];
    const int*   choices = (const int*)d_in[2];
    const float* W1 = (const float*)d_in[3];
    const float* b1 = (const float*)d_in[4];
    const float* W2 = (const float*)d_in[5];
    const float* b2 = (const float*)d_in[6];
    const float* W3 = (const float*)d_in[7];
    const float* b3 = (const float*)d_in[8];
    const float* fcw = (const float*)d_in[9];
    const float* fcb = (const float*)d_in[10];
    float* out = (float*)d_out;

    int n = in_sizes[0] / 3;
    int E = in_sizes[1] / 2;
    const int* row = ei;
    const int* col = ei + E;

    int nblkN = (n + BLK - 1) / BLK;           // 391
    int nblk128 = (n + 127) / 128;             // 782   (fused kernel grid)
    int nbuck = (n + (1 << BSH) - 1) >> BSH;   // 391 buckets of 256 nodes
    int nblkBin = (E + EB - 1) / EB;           // 391 binning blocks

    // workspace layout (16B aligned slices); ws_size is ~268 MB, plenty
    char* ws = (char*)d_ws;
    size_t o = 0;
    auto alloc = [&](size_t bytes) { char* p = ws + o; o += (bytes + 15) & ~(size_t)15; return p; };
    int*   degi   = (int*)  alloc((size_t)n * 4);
    int*   offs   = (int*)  alloc((size_t)n * 4);
    float* dinv   = (float*)alloc((size_t)n * 4);
    float* hws3   = (float*)alloc((size_t)(n + 1) * 4);  // +1: dummy node
    float* cbuf   = (float*)alloc((size_t)n * 4);
    float* bmax   = (float*)alloc(8192);       // >= nblk128 floats
    float* bsum   = (float*)alloc(8192);
    int*   gcur   = (int*)  alloc(NB * 4);
    float* scal   = (float*)alloc(256);   // [1..16]=pool
    float* pool   = scal + 1;
    __half* xs    = (__half*)alloc((size_t)(n + 1) * 4 * 2);  // half4/node +dummy
    size_t hw_bytes = (size_t)(n + 1) * 16 * 2;          // hwsB (fp16) + dummy
    size_t pk_bytes = (size_t)NB * CAP * 4;              // packed (capacity layout)
    char*  blob   = alloc(hw_bytes > pk_bytes ? hw_bytes : pk_bytes);
    int*    packed = (int*)blob;          // build phase only; dead before agg1
    __half* hwsB   = (__half*)blob;
    int*   srcs   = (int*)  alloc((size_t)NB * SCAP * 4);    // capacity layout
    int*   bar    = (int*)  alloc(16);    // grid-barrier counter
    (void)ws_size;  // ~65 MB used

    // ---- build (2 passes over edges; no per-edge global atomics) ----
    k_init<<<1, NB, 0, stream>>>(gcur, scal, bar);
    k_bin<<<nblkBin, BINTH, 0, stream>>>(row, col, gcur, packed, E);

    // ---- fused place + 3 GCN layers + softmax/value ----
    k_fused<<<nblk128, BLK, 0, stream>>>(
        packed, gcur, x, degi, offs, dinv, xs, srcs,
        b1, W1, W2, hwsB, b2, W3, hws3, pool,
        b3, choices, cbuf, bmax, bsum, fcw, fcb, out,
        bar, n, nbuck, nblkN);
}

// Round 3
// 214.413 us; speedup vs baseline: 5.6769x; 5.6769x over previous
//
#include <hip/hip_runtime.h>
#include <hip/hip_fp16.h>
#include <math.h>

#define BLK 256

// ---------------------------------------------------------------------------
// GCNPolicyNetwork: 3-layer improved-GCN + masked softmax + mean-pool value.
// R3 (this session): REVERT the R1 persistent-kernel fusion (grid barriers
// cost ~240 us each: per-block agent fences = full L2 wb/inv x782 + 782-way
// spin contention on one line — dispatch boundaries are strictly cheaper).
// Back to the verified multi-kernel pipeline, plus ONE change:
//   k_place now scatters srcs into an LDS window (48 KB) and flushes it
//   with fully-coalesced streaming writes, replacing 3.2M independent 4B
//   global scatter-writes (one 64B L2 line each) with LDS-rate scatters +
//   ~13 MB of coalesced global writes. Same trick k_bin already uses.
// ---------------------------------------------------------------------------

#define BSH 8                    // 256 nodes per bucket
#define NB 512                   // bucket-array size (nbuck=391 <= 512)
#define CAP 10240                // packed[] capacity per bucket (mean ~8184)
#define SCAP 12288               // srcs[] capacity per bucket (CAP + 8*256 pad)
#define EB 8192                  // edges per binning block
#define BINTH 1024               // k_bin block size

// ---- fp16 payload helpers ----
__device__ inline float4 load_h4(const __half* base, int node, int sub) {
    const uint2* p = reinterpret_cast<const uint2*>(base + ((size_t)node << 4)) + sub;
    uint2 u = *p;
    union { unsigned u; __half2 h; } a, b;
    a.u = u.x; b.u = u.y;
    float2 fa = __half22float2(a.h), fb = __half22float2(b.h);
    return make_float4(fa.x, fa.y, fb.x, fb.y);
}

__device__ inline void store_h4(__half* base, int node, int sub, float4 v) {
    union { unsigned u; __half2 h; } a, b;
    a.h = __floats2half2_rn(v.x, v.y);
    b.h = __floats2half2_rn(v.z, v.w);
    uint2 u; u.x = a.u; u.y = b.u;
    *(reinterpret_cast<uint2*>(base + ((size_t)node << 4)) + sub) = u;
}

// xs payload: half4 (dinv*x0, dinv*x1, dinv*x2, 0) = 8 B per node
__device__ inline float3 load_xs(const __half* xs, int node) {
    uint2 u = *reinterpret_cast<const uint2*>(xs + ((size_t)node << 2));
    union { unsigned u; __half2 h; } a, b;
    a.u = u.x; b.u = u.y;
    float2 fa = __half22float2(a.h), fb = __half22float2(b.h);
    return make_float3(fa.x, fa.y, fb.x);
}

// zero gcur[NB] + scal[18]
__global__ void k_init(int* __restrict__ gcur, float* __restrict__ scal) {
    int t = threadIdx.x;
    gcur[t] = 0;
    if (t < 18) scal[t] = 0.f;
}

// LDS multisplit of edges into 256-node buckets; reserve directly in the
// fixed-capacity packed[] layout (bucket b owns [b*CAP, b*CAP+cnt)).
__global__ void __launch_bounds__(BINTH) k_bin(const int* __restrict__ row,
                                               const int* __restrict__ col,
                                               int* __restrict__ gcur,
                                               int* __restrict__ packed, int E) {
    __shared__ int stage[EB];
    __shared__ unsigned short sbuk[EB];
    __shared__ int hist[NB];
    __shared__ int lscan[NB];
    __shared__ int cur[NB];
    __shared__ int gbase[NB];
    int tid = threadIdx.x;
    int base = blockIdx.x * EB;
    int cnt = min(EB, E - base);

    if (tid < NB) hist[tid] = 0;
    __syncthreads();
    for (int j = tid; j < cnt; j += BINTH) {
        int c = __builtin_nontemporal_load(col + base + j);
        atomicAdd(&hist[c >> BSH], 1);
    }
    __syncthreads();
    if (tid < NB) lscan[tid] = hist[tid];
    __syncthreads();
    for (int d = 1; d < NB; d <<= 1) {
        int t = (tid < NB && tid >= d) ? lscan[tid - d] : 0;
        __syncthreads();
        if (tid < NB && tid >= d) lscan[tid] += t;
        __syncthreads();
    }
    if (tid < NB) {
        int ex = lscan[tid] - hist[tid];
        lscan[tid] = ex;
        cur[tid] = ex;
    }
    __syncthreads();
    for (int j = tid; j < cnt; j += BINTH) {
        int c = __builtin_nontemporal_load(col + base + j);
        int r = __builtin_nontemporal_load(row + base + j);
        int b = c >> BSH;
        int p = atomicAdd(&cur[b], 1);
        stage[p] = (r << BSH) | (c & ((1 << BSH) - 1));
        sbuk[p] = (unsigned short)b;
    }
    __syncthreads();
    if (tid < NB && hist[tid] > 0)
        gbase[tid] = tid * CAP + atomicAdd(&gcur[tid], hist[tid]);
    __syncthreads();
    for (int j = tid; j < cnt; j += BINTH) {
        int b = sbuk[j];
        int pos = gbase[b] + (j - lscan[b]);
        packed[pos] = stage[j];
    }
}

// per-bucket: degree hist + scan of PADDED(x8) lengths -> degi/offs/dinv/xs,
// then scatter edges + dummy pads into an LDS window and flush coalesced.
__global__ void __launch_bounds__(BLK) k_place(const int* __restrict__ packed,
                                               const int* __restrict__ bcnt,
                                               const float* __restrict__ x,
                                               int* __restrict__ degi,
                                               int* __restrict__ offs,
                                               float* __restrict__ dinv,
                                               __half* __restrict__ xs,
                                               int* __restrict__ srcs, int n) {
    __shared__ int cnt[256];
    __shared__ int lcur[256];
    __shared__ int ssum[256];
    __shared__ int stg[SCAP];              // 48 KB LDS srcs window
    int tid = threadIdx.x;
    int b = blockIdx.x;
    int nb0 = b << BSH;
    cnt[tid] = 0;
    __syncthreads();
    int ecnt = bcnt[b];
    const int* pk = packed + (size_t)b * CAP;
    for (int j = tid; j < ecnt; j += BLK)
        atomicAdd(&cnt[pk[j] & 255], 1);
    __syncthreads();
    int c = cnt[tid];
    int pl = (c + 7) & ~7;                 // padded length (x8)
    ssum[tid] = pl;
    __syncthreads();
    for (int d = 1; d < 256; d <<= 1) {
        int t = (tid >= d) ? ssum[tid - d] : 0;
        __syncthreads();
        if (tid >= d) ssum[tid] += t;
        __syncthreads();
    }
    int Arel = ssum[tid] - pl;             // LDS-relative base for this node
    lcur[tid] = Arel;
    int A = b * SCAP + Arel;               // absolute aligned base for node
    int valid = min(n - nb0, 256);
    int i = nb0 + tid;
    if (tid < valid) {
        degi[i] = pl;
        offs[i] = A;
        float di = rsqrtf((float)c + 2.0f);
        dinv[i] = di;
        float x0 = x[i * 3 + 0], x1 = x[i * 3 + 1], x2 = x[i * 3 + 2];
        union { unsigned u; __half2 h; } a2, b2;
        a2.h = __floats2half2_rn(di * x0, di * x1);
        b2.h = __floats2half2_rn(di * x2, 0.f);
        uint2 u; u.x = a2.u; u.y = b2.u;
        *reinterpret_cast<uint2*>(xs + ((size_t)i << 2)) = u;
        for (int k = c; k < pl; k++) stg[Arel + k] = n;   // dummy pads (LDS)
    }
    if (b == 0 && tid == 0) {              // zero the dummy xs payload
        uint2 z; z.x = 0u; z.y = 0u;
        *reinterpret_cast<uint2*>(xs + ((size_t)n << 2)) = z;
    }
    __syncthreads();
    for (int j = tid; j < ecnt; j += BLK) {
        int v = pk[j];
        int slot = atomicAdd(&lcur[v & 255], 1);
        stg[slot] = v >> BSH;              // LDS scatter (was global scatter)
    }
    __syncthreads();
    int total = ssum[255];                 // total padded ints this bucket
    int gb = b * SCAP;
    for (int j = tid; j < total; j += BLK) // coalesced flush LDS -> global
        srcs[gb + j] = stg[j];
}

// layer-1: DUAL-NODE rank-3 aggregation of xs, then @W1+relu, @W2 -> hwsB.
// Team of 4 lanes walks nodes iA and iB=iA+64 together (128 nodes/block).
__global__ void __launch_bounds__(BLK) k_agg1(const __half* __restrict__ xs,
                                              const int* __restrict__ offs,
                                              const int* __restrict__ degi,
                                              const int* __restrict__ srcs,
                                              const float* __restrict__ dinv,
                                              const float* __restrict__ b1,
                                              const float* __restrict__ W1,
                                              const float* __restrict__ W2,
                                              __half* __restrict__ hwsB, int n) {
    __shared__ float w1[48];
    __shared__ float w2[256];
    __shared__ float bb[16];
    __shared__ float hbuf[128][17];
    int tid = threadIdx.x;
    w2[tid] = W2[tid];
    if (tid < 48) w1[tid] = W1[tid];
    if (tid < 16) bb[tid] = b1[tid];
    if (blockIdx.x == 0 && tid < 8)        // zero the dummy hwsB payload (32 B)
        reinterpret_cast<unsigned*>(hwsB + ((size_t)n << 4))[tid] = 0u;
    __syncthreads();
    int nl = tid >> 2, sub = tid & 3;
    int iA = blockIdx.x * 128 + nl;
    int iB = iA + 64;
    bool actA = (iA < n), actB = (iB < n);
    int AA = actA ? offs[iA] : 0;
    int AB = actB ? offs[iB] : 0;
    int plA = actA ? degi[iA] : 0;
    int plB = actB ? degi[iB] : 0;
    float axA = 0.f, ayA = 0.f, azA = 0.f;
    float axB = 0.f, ayB = 0.f, azB = 0.f;
    int plM = max(plA, plB);
    for (int j = 4 * sub; j < plM; j += 16) {
        int ja = min(j, max(plA - 4, 0));
        int jb = min(j, max(plB - 4, 0));
        int4 sa = *reinterpret_cast<const int4*>(srcs + AA + ja);
        int4 sb = *reinterpret_cast<const int4*>(srcs + AB + jb);
        if (j >= plA) sa = make_int4(n, n, n, n);
        if (j >= plB) sb = make_int4(n, n, n, n);
        float3 qa0 = load_xs(xs, sa.x);
        float3 qa1 = load_xs(xs, sa.y);
        float3 qa2 = load_xs(xs, sa.z);
        float3 qa3 = load_xs(xs, sa.w);
        float3 qb0 = load_xs(xs, sb.x);
        float3 qb1 = load_xs(xs, sb.y);
        float3 qb2 = load_xs(xs, sb.z);
        float3 qb3 = load_xs(xs, sb.w);
        axA += qa0.x + qa1.x + qa2.x + qa3.x;
        ayA += qa0.y + qa1.y + qa2.y + qa3.y;
        azA += qa0.z + qa1.z + qa2.z + qa3.z;
        axB += qb0.x + qb1.x + qb2.x + qb3.x;
        ayB += qb0.y + qb1.y + qb2.y + qb3.y;
        azB += qb0.z + qb1.z + qb2.z + qb3.z;
    }
    axA += __shfl_xor(axA, 1); ayA += __shfl_xor(ayA, 1); azA += __shfl_xor(azA, 1);
    axA += __shfl_xor(axA, 2); ayA += __shfl_xor(ayA, 2); azA += __shfl_xor(azA, 2);
    axB += __shfl_xor(axB, 1); ayB += __shfl_xor(ayB, 1); azB += __shfl_xor(azB, 1);
    axB += __shfl_xor(axB, 2); ayB += __shfl_xor(ayB, 2); azB += __shfl_xor(azB, 2);
    float diA = 0.f, diB = 0.f;
    if (actA) {
        diA = dinv[iA];
        float3 s = load_xs(xs, iA);
        float ax = axA + 2.f * s.x, ay = ayA + 2.f * s.y, az = azA + 2.f * s.z;
#pragma unroll
        for (int k = 0; k < 4; k++) {
            int f = sub * 4 + k;
            float hv = diA * (ax * w1[f] + ay * w1[16 + f] + az * w1[32 + f]) + bb[f];
            hbuf[nl][f] = fmaxf(hv, 0.f);
        }
    }
    if (actB) {
        diB = dinv[iB];
        float3 s = load_xs(xs, iB);
        float ax = axB + 2.f * s.x, ay = ayB + 2.f * s.y, az = azB + 2.f * s.z;
#pragma unroll
        for (int k = 0; k < 4; k++) {
            int f = sub * 4 + k;
            float hv = diB * (ax * w1[f] + ay * w1[16 + f] + az * w1[32 + f]) + bb[f];
            hbuf[64 + nl][f] = fmaxf(hv, 0.f);
        }
    }
    __syncthreads();
    if (actA) {
        const float* hn = hbuf[nl];
        float s0 = 0.f, s1 = 0.f, s2 = 0.f, s3 = 0.f;
#pragma unroll
        for (int f = 0; f < 16; f++) {
            float hv = hn[f];
            const float4 wq = *(const float4*)&w2[f * 16 + sub * 4];
            s0 += hv * wq.x; s1 += hv * wq.y; s2 += hv * wq.z; s3 += hv * wq.w;
        }
        store_h4(hwsB, iA, sub, make_float4(diA * s0, diA * s1, diA * s2, diA * s3));
    }
    if (actB) {
        const float* hn = hbuf[64 + nl];
        float s0 = 0.f, s1 = 0.f, s2 = 0.f, s3 = 0.f;
#pragma unroll
        for (int f = 0; f < 16; f++) {
            float hv = hn[f];
            const float4 wq = *(const float4*)&w2[f * 16 + sub * 4];
            s0 += hv * wq.x; s1 += hv * wq.y; s2 += hv * wq.z; s3 += hv * wq.w;
        }
        store_h4(hwsB, iB, sub, make_float4(diB * s0, diB * s1, diB * s2, diB * s3));
    }
}

// layer-2: DUAL-NODE interleaved gather + relu + pool + layer-3 transform.
__global__ void __launch_bounds__(BLK) k_agg2(const __half* __restrict__ hwsB,
                                              const int* __restrict__ offs,
                                              const int* __restrict__ degi,
                                              const int* __restrict__ srcs,
                                              const float* __restrict__ dinv,
                                              const float* __restrict__ b2,
                                              const float* __restrict__ W3,
                                              float* __restrict__ hws3,
                                              float* __restrict__ pool, int n) {
    __shared__ float w3[16];
    __shared__ float bb[16];
    __shared__ float lp[16];
    int tid = threadIdx.x;
    if (tid < 16) { w3[tid] = W3[tid]; bb[tid] = b2[tid]; lp[tid] = 0.f; }
    if (blockIdx.x == 0 && tid == 0) hws3[n] = 0.f;   // zero dummy hws3
    __syncthreads();
    int nl = tid >> 2, sub = tid & 3;
    int iA = blockIdx.x * 128 + nl;
    int iB = iA + 64;
    bool actA = (iA < n), actB = (iB < n);
    float diA = actA ? dinv[iA] : 0.f;
    float diB = actB ? dinv[iB] : 0.f;
    int AA = actA ? offs[iA] : 0;
    int AB = actB ? offs[iB] : 0;
    int plA = actA ? degi[iA] : 0;
    int plB = actB ? degi[iB] : 0;
    float4 z4 = make_float4(0.f, 0.f, 0.f, 0.f);
    float4 sA = actA ? load_h4(hwsB, iA, sub) : z4;
    float4 sB = actB ? load_h4(hwsB, iB, sub) : z4;
    float4 accA = make_float4(2.f * sA.x, 2.f * sA.y, 2.f * sA.z, 2.f * sA.w);
    float4 accB = make_float4(2.f * sB.x, 2.f * sB.y, 2.f * sB.z, 2.f * sB.w);
    float4 a1A = z4, a1B = z4;
    int plM = max(plA, plB);
    for (int j = 0; j < plM; j += 8) {
        int ja = min(j, max(plA - 8, 0));
        int jb = min(j, max(plB - 8, 0));
        int4 sa0 = *reinterpret_cast<const int4*>(srcs + AA + ja);
        int4 sa1 = *reinterpret_cast<const int4*>(srcs + AA + ja + 4);
        int4 sb0 = *reinterpret_cast<const int4*>(srcs + AB + jb);
        int4 sb1 = *reinterpret_cast<const int4*>(srcs + AB + jb + 4);
        if (j >= plA) { sa0 = make_int4(n, n, n, n); sa1 = sa0; }
        if (j >= plB) { sb0 = make_int4(n, n, n, n); sb1 = sb0; }
        float4 qa0 = load_h4(hwsB, sa0.x, sub);
        float4 qa1 = load_h4(hwsB, sa0.y, sub);
        float4 qa2 = load_h4(hwsB, sa0.z, sub);
        float4 qa3 = load_h4(hwsB, sa0.w, sub);
        float4 qa4 = load_h4(hwsB, sa1.x, sub);
        float4 qa5 = load_h4(hwsB, sa1.y, sub);
        float4 qa6 = load_h4(hwsB, sa1.z, sub);
        float4 qa7 = load_h4(hwsB, sa1.w, sub);
        float4 qb0 = load_h4(hwsB, sb0.x, sub);
        float4 qb1 = load_h4(hwsB, sb0.y, sub);
        float4 qb2 = load_h4(hwsB, sb0.z, sub);
        float4 qb3 = load_h4(hwsB, sb0.w, sub);
        float4 qb4 = load_h4(hwsB, sb1.x, sub);
        float4 qb5 = load_h4(hwsB, sb1.y, sub);
        float4 qb6 = load_h4(hwsB, sb1.z, sub);
        float4 qb7 = load_h4(hwsB, sb1.w, sub);
        accA.x += qa0.x + qa2.x + qa4.x + qa6.x;
        accA.y += qa0.y + qa2.y + qa4.y + qa6.y;
        accA.z += qa0.z + qa2.z + qa4.z + qa6.z;
        accA.w += qa0.w + qa2.w + qa4.w + qa6.w;
        a1A.x += qa1.x + qa3.x + qa5.x + qa7.x;
        a1A.y += qa1.y + qa3.y + qa5.y + qa7.y;
        a1A.z += qa1.z + qa3.z + qa5.z + qa7.z;
        a1A.w += qa1.w + qa3.w + qa5.w + qa7.w;
        accB.x += qb0.x + qb2.x + qb4.x + qb6.x;
        accB.y += qb0.y + qb2.y + qb4.y + qb6.y;
        accB.z += qb0.z + qb2.z + qb4.z + qb6.z;
        accB.w += qb0.w + qb2.w + qb4.w + qb6.w;
        a1B.x += qb1.x + qb3.x + qb5.x + qb7.x;
        a1B.y += qb1.y + qb3.y + qb5.y + qb7.y;
        a1B.z += qb1.z + qb3.z + qb5.z + qb7.z;
        a1B.w += qb1.w + qb3.w + qb5.w + qb7.w;
    }
    accA.x += a1A.x; accA.y += a1A.y; accA.z += a1A.z; accA.w += a1A.w;
    accB.x += a1B.x; accB.y += a1B.y; accB.z += a1B.z; accB.w += a1B.w;
    float4 hA = z4, hB = z4;
    if (actA) {
        hA.x = fmaxf(diA * accA.x + bb[sub * 4 + 0], 0.f);
        hA.y = fmaxf(diA * accA.y + bb[sub * 4 + 1], 0.f);
        hA.z = fmaxf(diA * accA.z + bb[sub * 4 + 2], 0.f);
        hA.w = fmaxf(diA * accA.w + bb[sub * 4 + 3], 0.f);
    }
    if (actB) {
        hB.x = fmaxf(diB * accB.x + bb[sub * 4 + 0], 0.f);
        hB.y = fmaxf(diB * accB.y + bb[sub * 4 + 1], 0.f);
        hB.z = fmaxf(diB * accB.z + bb[sub * 4 + 2], 0.f);
        hB.w = fmaxf(diB * accB.w + bb[sub * 4 + 3], 0.f);
    }
    float pA = hA.x * w3[sub * 4 + 0] + hA.y * w3[sub * 4 + 1]
             + hA.z * w3[sub * 4 + 2] + hA.w * w3[sub * 4 + 3];
    float pB = hB.x * w3[sub * 4 + 0] + hB.y * w3[sub * 4 + 1]
             + hB.z * w3[sub * 4 + 2] + hB.w * w3[sub * 4 + 3];
    pA += __shfl_xor(pA, 1); pA += __shfl_xor(pA, 2);
    pB += __shfl_xor(pB, 1); pB += __shfl_xor(pB, 2);
    if (sub == 0) {
        if (actA) hws3[iA] = diA * pA;
        if (actB) hws3[iB] = diB * pB;
    }
    float4 hp = make_float4(hA.x + hB.x, hA.y + hB.y, hA.z + hB.z, hA.w + hB.w);
#pragma unroll
    for (int m = 4; m < 64; m <<= 1) {
        hp.x += __shfl_xor(hp.x, m);
        hp.y += __shfl_xor(hp.y, m);
        hp.z += __shfl_xor(hp.z, m);
        hp.w += __shfl_xor(hp.w, m);
    }
    if ((tid & 63) < 4) {
        atomicAdd(&lp[sub * 4 + 0], hp.x);
        atomicAdd(&lp[sub * 4 + 1], hp.y);
        atomicAdd(&lp[sub * 4 + 2], hp.z);
        atomicAdd(&lp[sub * 4 + 3], hp.w);
    }
    __syncthreads();
    if (tid < 16) atomicAdd(&pool[tid], lp[tid]);
}

// layer-3: DUAL-NODE scalar aggregation (8-index chunks per lane, stride 32)
// -> logits; per-block (max, sum-exp) for the fused softmax.
__global__ void __launch_bounds__(BLK) k_agg3(const float* __restrict__ hws3,
                                              const int* __restrict__ offs,
                                              const int* __restrict__ degi,
                                              const int* __restrict__ srcs,
                                              const float* __restrict__ dinv,
                                              const float* __restrict__ b3,
                                              const int* __restrict__ choices,
                                              float* __restrict__ cbuf,
                                              float* __restrict__ bmax,
                                              float* __restrict__ bsum, int n) {
    __shared__ float red[BLK];
    int tid = threadIdx.x;
    int nl = tid >> 2, sub = tid & 3;
    int iA = blockIdx.x * 128 + nl;
    int iB = iA + 64;
    bool actA = (iA < n), actB = (iB < n);
    int AA = actA ? offs[iA] : 0;
    int AB = actB ? offs[iB] : 0;
    int plA = actA ? degi[iA] : 0;
    int plB = actB ? degi[iB] : 0;
    float sA0 = 0.f, sA1 = 0.f, sB0 = 0.f, sB1 = 0.f;
    int plM = max(plA, plB);
    for (int j = 8 * sub; j < plM; j += 32) {
        int ja = min(j, max(plA - 8, 0));
        int jb = min(j, max(plB - 8, 0));
        int4 sa0 = *reinterpret_cast<const int4*>(srcs + AA + ja);
        int4 sa1 = *reinterpret_cast<const int4*>(srcs + AA + ja + 4);
        int4 sb0 = *reinterpret_cast<const int4*>(srcs + AB + jb);
        int4 sb1 = *reinterpret_cast<const int4*>(srcs + AB + jb + 4);
        if (j >= plA) { sa0 = make_int4(n, n, n, n); sa1 = sa0; }
        if (j >= plB) { sb0 = make_int4(n, n, n, n); sb1 = sb0; }
        sA0 += hws3[sa0.x] + hws3[sa0.z] + hws3[sa1.x] + hws3[sa1.z];
        sA1 += hws3[sa0.y] + hws3[sa0.w] + hws3[sa1.y] + hws3[sa1.w];
        sB0 += hws3[sb0.x] + hws3[sb0.z] + hws3[sb1.x] + hws3[sb1.z];
        sB1 += hws3[sb0.y] + hws3[sb0.w] + hws3[sb1.y] + hws3[sb1.w];
    }
    float sA = sA0 + sA1, sB = sB0 + sB1;
    sA += __shfl_xor(sA, 1); sA += __shfl_xor(sA, 2);
    sB += __shfl_xor(sB, 1); sB += __shfl_xor(sB, 2);
    float lA = -INFINITY, lB = -INFINITY;
    if (sub == 0) {
        if (actA) {
            float c = dinv[iA] * (sA + 2.f * hws3[iA]) + b3[0];
            cbuf[iA] = c;
            if (choices[iA] != 0) lA = c;
        }
        if (actB) {
            float c = dinv[iB] * (sB + 2.f * hws3[iB]) + b3[0];
            cbuf[iB] = c;
            if (choices[iB] != 0) lB = c;
        }
    }
    red[tid] = fmaxf(lA, lB);
    __syncthreads();
    for (int d = BLK / 2; d > 0; d >>= 1) {
        if (tid < d) red[tid] = fmaxf(red[tid], red[tid + d]);
        __syncthreads();
    }
    float bm = red[0];
    __syncthreads();
    float es = 0.f;
    if (lA > -INFINITY) es += expf(lA - bm);
    if (lB > -INFINITY) es += expf(lB - bm);
    red[tid] = es;
    __syncthreads();
    for (int d = BLK / 2; d > 0; d >>= 1) {
        if (tid < d) red[tid] += red[tid + d];
        __syncthreads();
    }
    if (tid == 0) { bmax[blockIdx.x] = bm; bsum[blockIdx.x] = red[0]; }
}

// final: every block redundantly combines per-block (max,sum) -> (M,S),
// then writes probabilities; block 0 writes the value head.
__global__ void __launch_bounds__(BLK) k_final(const float* __restrict__ cbuf,
                                               const int* __restrict__ choices,
                                               const float* __restrict__ bmax,
                                               const float* __restrict__ bsum,
                                               const float* __restrict__ pool,
                                               const float* __restrict__ fcw,
                                               const float* __restrict__ fcb,
                                               float* __restrict__ out,
                                               int nblk, int n) {
    __shared__ float red[BLK];
    __shared__ float MS[2];
    int tid = threadIdx.x;
    float m = -INFINITY;
    for (int i = tid; i < nblk; i += BLK) m = fmaxf(m, bmax[i]);
    red[tid] = m;
    __syncthreads();
    for (int d = BLK / 2; d > 0; d >>= 1) {
        if (tid < d) red[tid] = fmaxf(red[tid], red[tid + d]);
        __syncthreads();
    }
    float M = red[0];
    __syncthreads();
    float s = 0.f;
    for (int i = tid; i < nblk; i += BLK) {
        float bm = bmax[i];
        if (bm > -INFINITY) s += bsum[i] * expf(bm - M);
    }
    red[tid] = s;
    __syncthreads();
    for (int d = BLK / 2; d > 0; d >>= 1) {
        if (tid < d) red[tid] += red[tid + d];
        __syncthreads();
    }
    if (tid == 0) { MS[0] = M; MS[1] = red[0]; }
    __syncthreads();
    float Mv = MS[0], Sv = MS[1];
    int i = blockIdx.x * BLK + tid;
    if (i < n) {
        float p = 0.0f;
        if (choices[i] != 0) p = expf(cbuf[i] - Mv) / Sv;
        out[i] = p;
    }
    if (blockIdx.x == 0 && tid == 0) {
        float invn = 1.0f / (float)n;
        float v = 0.0f;
#pragma unroll
        for (int f = 0; f < 16; f++) v += (pool[f] * invn) * fcw[f];
        out[n] = v + fcb[0];
    }
}

extern "C" void kernel_launch(void* const* d_in, const int* in_sizes, int n_in,
                              void* d_out, int out_size, void* d_ws, size_t ws_size,
                              hipStream_t stream) {
    const float* x       = (const float*)d_in[0];
    const int*   ei      = (const int*)d_in[1];
    const int*   choices = (const int*)d_in[2];
    const float* W1 = (const float*)d_in[3];
    const float* b1 = (const float*)d_in[4];
    const float* W2 = (const float*)d_in[5];
    const float* b2 = (const float*)d_in[6];
    const float* W3 = (const float*)d_in[7];
    const float* b3 = (const float*)d_in[8];
    const float* fcw = (const float*)d_in[9];
    const float* fcb = (const float*)d_in[10];
    float* out = (float*)d_out;

    int n = in_sizes[0] / 3;
    int E = in_sizes[1] / 2;
    const int* row = ei;
    const int* col = ei + E;

    int nblkN = (n + BLK - 1) / BLK;           // 391
    int nblk128 = (n + 127) / 128;             // 782   (dual-node kernels)
    int nbuck = (n + (1 << BSH) - 1) >> BSH;   // 391 buckets of 256 nodes
    int nblkBin = (E + EB - 1) / EB;           // 391 binning blocks

    // workspace layout (16B aligned slices); ws_size is ~268 MB, plenty
    char* ws = (char*)d_ws;
    size_t o = 0;
    auto alloc = [&](size_t bytes) { char* p = ws + o; o += (bytes + 15) & ~(size_t)15; return p; };
    int*   degi   = (int*)  alloc((size_t)n * 4);
    int*   offs   = (int*)  alloc((size_t)n * 4);
    float* dinv   = (float*)alloc((size_t)n * 4);
    float* hws3   = (float*)alloc((size_t)(n + 1) * 4);  // +1: dummy node
    float* cbuf   = (float*)alloc((size_t)n * 4);
    float* bmax   = (float*)alloc(8192);       // >= nblk128 floats
    float* bsum   = (float*)alloc(8192);
    int*   gcur   = (int*)  alloc(NB * 4);
    float* scal   = (float*)alloc(256);   // [1..16]=pool
    float* pool   = scal + 1;
    __half* xs    = (__half*)alloc((size_t)(n + 1) * 4 * 2);  // half4/node +dummy
    size_t hw_bytes = (size_t)(n + 1) * 16 * 2;          // hwsB (fp16) + dummy
    size_t pk_bytes = (size_t)NB * CAP * 4;              // packed (capacity layout)
    char*  blob   = alloc(hw_bytes > pk_bytes ? hw_bytes : pk_bytes);
    int*    packed = (int*)blob;          // build phase only; dead before k_agg1
    __half* hwsB   = (__half*)blob;
    int*   srcs   = (int*)  alloc((size_t)NB * SCAP * 4);    // capacity layout
    (void)ws_size;  // ~65 MB used

    // ---- build (2 passes over edges; no per-edge global atomics) ----
    k_init<<<1, NB, 0, stream>>>(gcur, scal);
    k_bin<<<nblkBin, BINTH, 0, stream>>>(row, col, gcur, packed, E);
    k_place<<<nbuck, BLK, 0, stream>>>(packed, gcur, x, degi, offs, dinv, xs, srcs, n);

    // ---- GCN layers (all dual-node) ----
    k_agg1<<<nblk128, BLK, 0, stream>>>(xs, offs, degi, srcs, dinv, b1, W1, W2, hwsB, n);
    k_agg2<<<nblk128, BLK, 0, stream>>>(hwsB, offs, degi, srcs, dinv, b2, W3, hws3, pool, n);
    k_agg3<<<nblk128, BLK, 0, stream>>>(hws3, offs, degi, srcs, dinv, b3, choices, cbuf, bmax, bsum, n);

    // ---- softmax combine fused into final ----
    k_final<<<nblkN, BLK, 0, stream>>>(cbuf, choices, bmax, bsum, pool, fcw, fcb, out, nblk128, n);
}

// Round 4
// 210.518 us; speedup vs baseline: 5.7820x; 1.0185x over previous
//
#include <hip/hip_runtime.h>
#include <hip/hip_fp16.h>
#include <math.h>

#define BLK 256

// ---------------------------------------------------------------------------
// GCNPolicyNetwork: 3-layer improved-GCN + masked softmax + mean-pool value.
// R4 (this session): TLP boost for the gather kernels. k_agg1/k_agg2 move
// from dual-NODE teams (128 nodes/block, 782 blocks = 3 blocks/CU, 37%
// occupancy — grid-limited) to dual-STREAM single-node teams (64 nodes/block,
// 1563 blocks = 6 blocks/CU, ~75% occupancy). Per-lane MLP unchanged (two
// edge-chunks of the same node's list in flight); wave count doubles to hide
// the ~200-300cy random L2 gather latency. k_agg3 keeps the verified
// dual-node geometry (block-softmax layout tied to 782 blocks).
// R3: k_place scatters srcs via a 48KB LDS window, coalesced flush (-10us).
// ---------------------------------------------------------------------------

#define BSH 8                    // 256 nodes per bucket
#define NB 512                   // bucket-array size (nbuck=391 <= 512)
#define CAP 10240                // packed[] capacity per bucket (mean ~8184)
#define SCAP 12288               // srcs[] capacity per bucket (CAP + 8*256 pad)
#define EB 8192                  // edges per binning block
#define BINTH 1024               // k_bin block size

// ---- fp16 payload helpers ----
__device__ inline float4 load_h4(const __half* base, int node, int sub) {
    const uint2* p = reinterpret_cast<const uint2*>(base + ((size_t)node << 4)) + sub;
    uint2 u = *p;
    union { unsigned u; __half2 h; } a, b;
    a.u = u.x; b.u = u.y;
    float2 fa = __half22float2(a.h), fb = __half22float2(b.h);
    return make_float4(fa.x, fa.y, fb.x, fb.y);
}

__device__ inline void store_h4(__half* base, int node, int sub, float4 v) {
    union { unsigned u; __half2 h; } a, b;
    a.h = __floats2half2_rn(v.x, v.y);
    b.h = __floats2half2_rn(v.z, v.w);
    uint2 u; u.x = a.u; u.y = b.u;
    *(reinterpret_cast<uint2*>(base + ((size_t)node << 4)) + sub) = u;
}

// xs payload: half4 (dinv*x0, dinv*x1, dinv*x2, 0) = 8 B per node
__device__ inline float3 load_xs(const __half* xs, int node) {
    uint2 u = *reinterpret_cast<const uint2*>(xs + ((size_t)node << 2));
    union { unsigned u; __half2 h; } a, b;
    a.u = u.x; b.u = u.y;
    float2 fa = __half22float2(a.h), fb = __half22float2(b.h);
    return make_float3(fa.x, fa.y, fb.x);
}

// zero gcur[NB] + scal[18]
__global__ void k_init(int* __restrict__ gcur, float* __restrict__ scal) {
    int t = threadIdx.x;
    gcur[t] = 0;
    if (t < 18) scal[t] = 0.f;
}

// LDS multisplit of edges into 256-node buckets; reserve directly in the
// fixed-capacity packed[] layout (bucket b owns [b*CAP, b*CAP+cnt)).
__global__ void __launch_bounds__(BINTH) k_bin(const int* __restrict__ row,
                                               const int* __restrict__ col,
                                               int* __restrict__ gcur,
                                               int* __restrict__ packed, int E) {
    __shared__ int stage[EB];
    __shared__ unsigned short sbuk[EB];
    __shared__ int hist[NB];
    __shared__ int lscan[NB];
    __shared__ int cur[NB];
    __shared__ int gbase[NB];
    int tid = threadIdx.x;
    int base = blockIdx.x * EB;
    int cnt = min(EB, E - base);

    if (tid < NB) hist[tid] = 0;
    __syncthreads();
    for (int j = tid; j < cnt; j += BINTH) {
        int c = __builtin_nontemporal_load(col + base + j);
        atomicAdd(&hist[c >> BSH], 1);
    }
    __syncthreads();
    if (tid < NB) lscan[tid] = hist[tid];
    __syncthreads();
    for (int d = 1; d < NB; d <<= 1) {
        int t = (tid < NB && tid >= d) ? lscan[tid - d] : 0;
        __syncthreads();
        if (tid < NB && tid >= d) lscan[tid] += t;
        __syncthreads();
    }
    if (tid < NB) {
        int ex = lscan[tid] - hist[tid];
        lscan[tid] = ex;
        cur[tid] = ex;
    }
    __syncthreads();
    for (int j = tid; j < cnt; j += BINTH) {
        int c = __builtin_nontemporal_load(col + base + j);
        int r = __builtin_nontemporal_load(row + base + j);
        int b = c >> BSH;
        int p = atomicAdd(&cur[b], 1);
        stage[p] = (r << BSH) | (c & ((1 << BSH) - 1));
        sbuk[p] = (unsigned short)b;
    }
    __syncthreads();
    if (tid < NB && hist[tid] > 0)
        gbase[tid] = tid * CAP + atomicAdd(&gcur[tid], hist[tid]);
    __syncthreads();
    for (int j = tid; j < cnt; j += BINTH) {
        int b = sbuk[j];
        int pos = gbase[b] + (j - lscan[b]);
        packed[pos] = stage[j];
    }
}

// per-bucket: degree hist + scan of PADDED(x8) lengths -> degi/offs/dinv/xs,
// then scatter edges + dummy pads into an LDS window and flush coalesced.
__global__ void __launch_bounds__(BLK) k_place(const int* __restrict__ packed,
                                               const int* __restrict__ bcnt,
                                               const float* __restrict__ x,
                                               int* __restrict__ degi,
                                               int* __restrict__ offs,
                                               float* __restrict__ dinv,
                                               __half* __restrict__ xs,
                                               int* __restrict__ srcs, int n) {
    __shared__ int cnt[256];
    __shared__ int lcur[256];
    __shared__ int ssum[256];
    __shared__ int stg[SCAP];              // 48 KB LDS srcs window
    int tid = threadIdx.x;
    int b = blockIdx.x;
    int nb0 = b << BSH;
    cnt[tid] = 0;
    __syncthreads();
    int ecnt = bcnt[b];
    const int* pk = packed + (size_t)b * CAP;
    for (int j = tid; j < ecnt; j += BLK)
        atomicAdd(&cnt[pk[j] & 255], 1);
    __syncthreads();
    int c = cnt[tid];
    int pl = (c + 7) & ~7;                 // padded length (x8)
    ssum[tid] = pl;
    __syncthreads();
    for (int d = 1; d < 256; d <<= 1) {
        int t = (tid >= d) ? ssum[tid - d] : 0;
        __syncthreads();
        if (tid >= d) ssum[tid] += t;
        __syncthreads();
    }
    int Arel = ssum[tid] - pl;             // LDS-relative base for this node
    lcur[tid] = Arel;
    int A = b * SCAP + Arel;               // absolute aligned base for node
    int valid = min(n - nb0, 256);
    int i = nb0 + tid;
    if (tid < valid) {
        degi[i] = pl;
        offs[i] = A;
        float di = rsqrtf((float)c + 2.0f);
        dinv[i] = di;
        float x0 = x[i * 3 + 0], x1 = x[i * 3 + 1], x2 = x[i * 3 + 2];
        union { unsigned u; __half2 h; } a2, b2;
        a2.h = __floats2half2_rn(di * x0, di * x1);
        b2.h = __floats2half2_rn(di * x2, 0.f);
        uint2 u; u.x = a2.u; u.y = b2.u;
        *reinterpret_cast<uint2*>(xs + ((size_t)i << 2)) = u;
        for (int k = c; k < pl; k++) stg[Arel + k] = n;   // dummy pads (LDS)
    }
    if (b == 0 && tid == 0) {              // zero the dummy xs payload
        uint2 z; z.x = 0u; z.y = 0u;
        *reinterpret_cast<uint2*>(xs + ((size_t)n << 2)) = z;
    }
    __syncthreads();
    for (int j = tid; j < ecnt; j += BLK) {
        int v = pk[j];
        int slot = atomicAdd(&lcur[v & 255], 1);
        stg[slot] = v >> BSH;              // LDS scatter (was global scatter)
    }
    __syncthreads();
    int total = ssum[255];                 // total padded ints this bucket
    int gb = b * SCAP;
    for (int j = tid; j < total; j += BLK) // coalesced flush LDS -> global
        srcs[gb + j] = stg[j];
}

// layer-1: dual-STREAM rank-3 aggregation of xs, then @W1+relu, @W2 -> hwsB.
// One node per 4-lane team, 64 nodes/block, two 16-edge chunks in flight.
__global__ void __launch_bounds__(BLK) k_agg1(const __half* __restrict__ xs,
                                              const int* __restrict__ offs,
                                              const int* __restrict__ degi,
                                              const int* __restrict__ srcs,
                                              const float* __restrict__ dinv,
                                              const float* __restrict__ b1,
                                              const float* __restrict__ W1,
                                              const float* __restrict__ W2,
                                              __half* __restrict__ hwsB, int n) {
    __shared__ float w1[48];
    __shared__ float w2[256];
    __shared__ float bb[16];
    __shared__ float hbuf[64][17];
    int tid = threadIdx.x;
    w2[tid] = W2[tid];
    if (tid < 48) w1[tid] = W1[tid];
    if (tid < 16) bb[tid] = b1[tid];
    if (blockIdx.x == 0 && tid < 8)        // zero the dummy hwsB payload (32 B)
        reinterpret_cast<unsigned*>(hwsB + ((size_t)n << 4))[tid] = 0u;
    __syncthreads();
    int t = tid >> 2, sub = tid & 3;
    int i = blockIdx.x * 64 + t;
    bool act = (i < n);
    int A  = act ? offs[i] : 0;
    int pl = act ? degi[i] : 0;
    int o = 4 * sub;
    int clamp = max(pl - 4, 0);
    float ax0 = 0.f, ay0 = 0.f, az0 = 0.f;
    float ax1 = 0.f, ay1 = 0.f, az1 = 0.f;
    for (int j = 0; j < pl; j += 32) {
        int i0 = j + o;
        int i1 = j + 16 + o;
        int ja = min(i0, clamp);
        int jb = min(i1, clamp);
        int4 sa = *reinterpret_cast<const int4*>(srcs + A + ja);
        int4 sb = *reinterpret_cast<const int4*>(srcs + A + jb);
        if (i0 >= pl) sa = make_int4(n, n, n, n);
        if (i1 >= pl) sb = make_int4(n, n, n, n);
        float3 qa0 = load_xs(xs, sa.x);
        float3 qa1 = load_xs(xs, sa.y);
        float3 qa2 = load_xs(xs, sa.z);
        float3 qa3 = load_xs(xs, sa.w);
        float3 qb0 = load_xs(xs, sb.x);
        float3 qb1 = load_xs(xs, sb.y);
        float3 qb2 = load_xs(xs, sb.z);
        float3 qb3 = load_xs(xs, sb.w);
        ax0 += qa0.x + qa1.x + qa2.x + qa3.x;
        ay0 += qa0.y + qa1.y + qa2.y + qa3.y;
        az0 += qa0.z + qa1.z + qa2.z + qa3.z;
        ax1 += qb0.x + qb1.x + qb2.x + qb3.x;
        ay1 += qb0.y + qb1.y + qb2.y + qb3.y;
        az1 += qb0.z + qb1.z + qb2.z + qb3.z;
    }
    float ax = ax0 + ax1, ay = ay0 + ay1, az = az0 + az1;
    ax += __shfl_xor(ax, 1); ay += __shfl_xor(ay, 1); az += __shfl_xor(az, 1);
    ax += __shfl_xor(ax, 2); ay += __shfl_xor(ay, 2); az += __shfl_xor(az, 2);
    float di = 0.f;
    if (act) {
        di = dinv[i];
        float3 s = load_xs(xs, i);
        float axs = ax + 2.f * s.x, ays = ay + 2.f * s.y, azs = az + 2.f * s.z;
#pragma unroll
        for (int k = 0; k < 4; k++) {
            int f = sub * 4 + k;
            float hv = di * (axs * w1[f] + ays * w1[16 + f] + azs * w1[32 + f]) + bb[f];
            hbuf[t][f] = fmaxf(hv, 0.f);
        }
    }
    __syncthreads();
    if (act) {
        const float* hn = hbuf[t];
        float s0 = 0.f, s1 = 0.f, s2 = 0.f, s3 = 0.f;
#pragma unroll
        for (int f = 0; f < 16; f++) {
            float hv = hn[f];
            const float4 wq = *(const float4*)&w2[f * 16 + sub * 4];
            s0 += hv * wq.x; s1 += hv * wq.y; s2 += hv * wq.z; s3 += hv * wq.w;
        }
        store_h4(hwsB, i, sub, make_float4(di * s0, di * s1, di * s2, di * s3));
    }
}

// layer-2: dual-STREAM interleaved gather + relu + pool + layer-3 transform.
// One node per 4-lane team, 64 nodes/block, 16 payload loads in flight.
__global__ void __launch_bounds__(BLK) k_agg2(const __half* __restrict__ hwsB,
                                              const int* __restrict__ offs,
                                              const int* __restrict__ degi,
                                              const int* __restrict__ srcs,
                                              const float* __restrict__ dinv,
                                              const float* __restrict__ b2,
                                              const float* __restrict__ W3,
                                              float* __restrict__ hws3,
                                              float* __restrict__ pool, int n) {
    __shared__ float w3[16];
    __shared__ float bb[16];
    __shared__ float lp[16];
    int tid = threadIdx.x;
    if (tid < 16) { w3[tid] = W3[tid]; bb[tid] = b2[tid]; lp[tid] = 0.f; }
    if (blockIdx.x == 0 && tid == 0) hws3[n] = 0.f;   // zero dummy hws3
    __syncthreads();
    int t = tid >> 2, sub = tid & 3;
    int i = blockIdx.x * 64 + t;
    bool act = (i < n);
    float di = act ? dinv[i] : 0.f;
    int A  = act ? offs[i] : 0;
    int pl = act ? degi[i] : 0;
    float4 z4 = make_float4(0.f, 0.f, 0.f, 0.f);
    float4 s = act ? load_h4(hwsB, i, sub) : z4;
    float4 acc0 = make_float4(2.f * s.x, 2.f * s.y, 2.f * s.z, 2.f * s.w);
    float4 acc1 = z4, acc2 = z4, acc3 = z4;
    int clamp8 = max(pl - 8, 0);
    for (int j = 0; j < pl; j += 16) {
        int j1 = j + 8;
        int jb = min(j1, clamp8);
        int4 sa0 = *reinterpret_cast<const int4*>(srcs + A + j);
        int4 sa1 = *reinterpret_cast<const int4*>(srcs + A + j + 4);
        int4 sb0 = *reinterpret_cast<const int4*>(srcs + A + jb);
        int4 sb1 = *reinterpret_cast<const int4*>(srcs + A + jb + 4);
        if (j1 >= pl) { sb0 = make_int4(n, n, n, n); sb1 = sb0; }
        float4 qa0 = load_h4(hwsB, sa0.x, sub);
        float4 qa1 = load_h4(hwsB, sa0.y, sub);
        float4 qa2 = load_h4(hwsB, sa0.z, sub);
        float4 qa3 = load_h4(hwsB, sa0.w, sub);
        float4 qa4 = load_h4(hwsB, sa1.x, sub);
        float4 qa5 = load_h4(hwsB, sa1.y, sub);
        float4 qa6 = load_h4(hwsB, sa1.z, sub);
        float4 qa7 = load_h4(hwsB, sa1.w, sub);
        float4 qb0 = load_h4(hwsB, sb0.x, sub);
        float4 qb1 = load_h4(hwsB, sb0.y, sub);
        float4 qb2 = load_h4(hwsB, sb0.z, sub);
        float4 qb3 = load_h4(hwsB, sb0.w, sub);
        float4 qb4 = load_h4(hwsB, sb1.x, sub);
        float4 qb5 = load_h4(hwsB, sb1.y, sub);
        float4 qb6 = load_h4(hwsB, sb1.z, sub);
        float4 qb7 = load_h4(hwsB, sb1.w, sub);
        acc0.x += qa0.x + qa2.x + qa4.x + qa6.x;
        acc0.y += qa0.y + qa2.y + qa4.y + qa6.y;
        acc0.z += qa0.z + qa2.z + qa4.z + qa6.z;
        acc0.w += qa0.w + qa2.w + qa4.w + qa6.w;
        acc1.x += qa1.x + qa3.x + qa5.x + qa7.x;
        acc1.y += qa1.y + qa3.y + qa5.y + qa7.y;
        acc1.z += qa1.z + qa3.z + qa5.z + qa7.z;
        acc1.w += qa1.w + qa3.w + qa5.w + qa7.w;
        acc2.x += qb0.x + qb2.x + qb4.x + qb6.x;
        acc2.y += qb0.y + qb2.y + qb4.y + qb6.y;
        acc2.z += qb0.z + qb2.z + qb4.z + qb6.z;
        acc2.w += qb0.w + qb2.w + qb4.w + qb6.w;
        acc3.x += qb1.x + qb3.x + qb5.x + qb7.x;
        acc3.y += qb1.y + qb3.y + qb5.y + qb7.y;
        acc3.z += qb1.z + qb3.z + qb5.z + qb7.z;
        acc3.w += qb1.w + qb3.w + qb5.w + qb7.w;
    }
    acc0.x += acc1.x + acc2.x + acc3.x;
    acc0.y += acc1.y + acc2.y + acc3.y;
    acc0.z += acc1.z + acc2.z + acc3.z;
    acc0.w += acc1.w + acc2.w + acc3.w;
    float4 hA = z4;
    if (act) {
        hA.x = fmaxf(di * acc0.x + bb[sub * 4 + 0], 0.f);
        hA.y = fmaxf(di * acc0.y + bb[sub * 4 + 1], 0.f);
        hA.z = fmaxf(di * acc0.z + bb[sub * 4 + 2], 0.f);
        hA.w = fmaxf(di * acc0.w + bb[sub * 4 + 3], 0.f);
    }
    float pA = hA.x * w3[sub * 4 + 0] + hA.y * w3[sub * 4 + 1]
             + hA.z * w3[sub * 4 + 2] + hA.w * w3[sub * 4 + 3];
    pA += __shfl_xor(pA, 1); pA += __shfl_xor(pA, 2);
    if (sub == 0 && act) hws3[i] = di * pA;
    float4 hp = hA;
#pragma unroll
    for (int m = 4; m < 64; m <<= 1) {
        hp.x += __shfl_xor(hp.x, m);
        hp.y += __shfl_xor(hp.y, m);
        hp.z += __shfl_xor(hp.z, m);
        hp.w += __shfl_xor(hp.w, m);
    }
    if ((tid & 63) < 4) {
        atomicAdd(&lp[sub * 4 + 0], hp.x);
        atomicAdd(&lp[sub * 4 + 1], hp.y);
        atomicAdd(&lp[sub * 4 + 2], hp.z);
        atomicAdd(&lp[sub * 4 + 3], hp.w);
    }
    __syncthreads();
    if (tid < 16) atomicAdd(&pool[tid], lp[tid]);
}

// layer-3: DUAL-NODE scalar aggregation (8-index chunks per lane, stride 32)
// -> logits; per-block (max, sum-exp) for the fused softmax.
__global__ void __launch_bounds__(BLK) k_agg3(const float* __restrict__ hws3,
                                              const int* __restrict__ offs,
                                              const int* __restrict__ degi,
                                              const int* __restrict__ srcs,
                                              const float* __restrict__ dinv,
                                              const float* __restrict__ b3,
                                              const int* __restrict__ choices,
                                              float* __restrict__ cbuf,
                                              float* __restrict__ bmax,
                                              float* __restrict__ bsum, int n) {
    __shared__ float red[BLK];
    int tid = threadIdx.x;
    int nl = tid >> 2, sub = tid & 3;
    int iA = blockIdx.x * 128 + nl;
    int iB = iA + 64;
    bool actA = (iA < n), actB = (iB < n);
    int AA = actA ? offs[iA] : 0;
    int AB = actB ? offs[iB] : 0;
    int plA = actA ? degi[iA] : 0;
    int plB = actB ? degi[iB] : 0;
    float sA0 = 0.f, sA1 = 0.f, sB0 = 0.f, sB1 = 0.f;
    int plM = max(plA, plB);
    for (int j = 8 * sub; j < plM; j += 32) {
        int ja = min(j, max(plA - 8, 0));
        int jb = min(j, max(plB - 8, 0));
        int4 sa0 = *reinterpret_cast<const int4*>(srcs + AA + ja);
        int4 sa1 = *reinterpret_cast<const int4*>(srcs + AA + ja + 4);
        int4 sb0 = *reinterpret_cast<const int4*>(srcs + AB + jb);
        int4 sb1 = *reinterpret_cast<const int4*>(srcs + AB + jb + 4);
        if (j >= plA) { sa0 = make_int4(n, n, n, n); sa1 = sa0; }
        if (j >= plB) { sb0 = make_int4(n, n, n, n); sb1 = sb0; }
        sA0 += hws3[sa0.x] + hws3[sa0.z] + hws3[sa1.x] + hws3[sa1.z];
        sA1 += hws3[sa0.y] + hws3[sa0.w] + hws3[sa1.y] + hws3[sa1.w];
        sB0 += hws3[sb0.x] + hws3[sb0.z] + hws3[sb1.x] + hws3[sb1.z];
        sB1 += hws3[sb0.y] + hws3[sb0.w] + hws3[sb1.y] + hws3[sb1.w];
    }
    float sA = sA0 + sA1, sB = sB0 + sB1;
    sA += __shfl_xor(sA, 1); sA += __shfl_xor(sA, 2);
    sB += __shfl_xor(sB, 1); sB += __shfl_xor(sB, 2);
    float lA = -INFINITY, lB = -INFINITY;
    if (sub == 0) {
        if (actA) {
            float c = dinv[iA] * (sA + 2.f * hws3[iA]) + b3[0];
            cbuf[iA] = c;
            if (choices[iA] != 0) lA = c;
        }
        if (actB) {
            float c = dinv[iB] * (sB + 2.f * hws3[iB]) + b3[0];
            cbuf[iB] = c;
            if (choices[iB] != 0) lB = c;
        }
    }
    red[tid] = fmaxf(lA, lB);
    __syncthreads();
    for (int d = BLK / 2; d > 0; d >>= 1) {
        if (tid < d) red[tid] = fmaxf(red[tid], red[tid + d]);
        __syncthreads();
    }
    float bm = red[0];
    __syncthreads();
    float es = 0.f;
    if (lA > -INFINITY) es += expf(lA - bm);
    if (lB > -INFINITY) es += expf(lB - bm);
    red[tid] = es;
    __syncthreads();
    for (int d = BLK / 2; d > 0; d >>= 1) {
        if (tid < d) red[tid] += red[tid + d];
        __syncthreads();
    }
    if (tid == 0) { bmax[blockIdx.x] = bm; bsum[blockIdx.x] = red[0]; }
}

// final: every block redundantly combines per-block (max,sum) -> (M,S),
// then writes probabilities; block 0 writes the value head.
__global__ void __launch_bounds__(BLK) k_final(const float* __restrict__ cbuf,
                                               const int* __restrict__ choices,
                                               const float* __restrict__ bmax,
                                               const float* __restrict__ bsum,
                                               const float* __restrict__ pool,
                                               const float* __restrict__ fcw,
                                               const float* __restrict__ fcb,
                                               float* __restrict__ out,
                                               int nblk, int n) {
    __shared__ float red[BLK];
    __shared__ float MS[2];
    int tid = threadIdx.x;
    float m = -INFINITY;
    for (int i = tid; i < nblk; i += BLK) m = fmaxf(m, bmax[i]);
    red[tid] = m;
    __syncthreads();
    for (int d = BLK / 2; d > 0; d >>= 1) {
        if (tid < d) red[tid] = fmaxf(red[tid], red[tid + d]);
        __syncthreads();
    }
    float M = red[0];
    __syncthreads();
    float s = 0.f;
    for (int i = tid; i < nblk; i += BLK) {
        float bm = bmax[i];
        if (bm > -INFINITY) s += bsum[i] * expf(bm - M);
    }
    red[tid] = s;
    __syncthreads();
    for (int d = BLK / 2; d > 0; d >>= 1) {
        if (tid < d) red[tid] += red[tid + d];
        __syncthreads();
    }
    if (tid == 0) { MS[0] = M; MS[1] = red[0]; }
    __syncthreads();
    float Mv = MS[0], Sv = MS[1];
    int i = blockIdx.x * BLK + tid;
    if (i < n) {
        float p = 0.0f;
        if (choices[i] != 0) p = expf(cbuf[i] - Mv) / Sv;
        out[i] = p;
    }
    if (blockIdx.x == 0 && tid == 0) {
        float invn = 1.0f / (float)n;
        float v = 0.0f;
#pragma unroll
        for (int f = 0; f < 16; f++) v += (pool[f] * invn) * fcw[f];
        out[n] = v + fcb[0];
    }
}

extern "C" void kernel_launch(void* const* d_in, const int* in_sizes, int n_in,
                              void* d_out, int out_size, void* d_ws, size_t ws_size,
                              hipStream_t stream) {
    const float* x       = (const float*)d_in[0];
    const int*   ei      = (const int*)d_in[1];
    const int*   choices = (const int*)d_in[2];
    const float* W1 = (const float*)d_in[3];
    const float* b1 = (const float*)d_in[4];
    const float* W2 = (const float*)d_in[5];
    const float* b2 = (const float*)d_in[6];
    const float* W3 = (const float*)d_in[7];
    const float* b3 = (const float*)d_in[8];
    const float* fcw = (const float*)d_in[9];
    const float* fcb = (const float*)d_in[10];
    float* out = (float*)d_out;

    int n = in_sizes[0] / 3;
    int E = in_sizes[1] / 2;
    const int* row = ei;
    const int* col = ei + E;

    int nblkN = (n + BLK - 1) / BLK;           // 391
    int nblk64 = (n + 63) / 64;                // 1563  (dual-stream kernels)
    int nblk128 = (n + 127) / 128;             // 782   (k_agg3)
    int nbuck = (n + (1 << BSH) - 1) >> BSH;   // 391 buckets of 256 nodes
    int nblkBin = (E + EB - 1) / EB;           // 391 binning blocks

    // workspace layout (16B aligned slices); ws_size is ~268 MB, plenty
    char* ws = (char*)d_ws;
    size_t o = 0;
    auto alloc = [&](size_t bytes) { char* p = ws + o; o += (bytes + 15) & ~(size_t)15; return p; };
    int*   degi   = (int*)  alloc((size_t)n * 4);
    int*   offs   = (int*)  alloc((size_t)n * 4);
    float* dinv   = (float*)alloc((size_t)n * 4);
    float* hws3   = (float*)alloc((size_t)(n + 1) * 4);  // +1: dummy node
    float* cbuf   = (float*)alloc((size_t)n * 4);
    float* bmax   = (float*)alloc(8192);       // >= nblk128 floats
    float* bsum   = (float*)alloc(8192);
    int*   gcur   = (int*)  alloc(NB * 4);
    float* scal   = (float*)alloc(256);   // [1..16]=pool
    float* pool   = scal + 1;
    __half* xs    = (__half*)alloc((size_t)(n + 1) * 4 * 2);  // half4/node +dummy
    size_t hw_bytes = (size_t)(n + 1) * 16 * 2;          // hwsB (fp16) + dummy
    size_t pk_bytes = (size_t)NB * CAP * 4;              // packed (capacity layout)
    char*  blob   = alloc(hw_bytes > pk_bytes ? hw_bytes : pk_bytes);
    int*    packed = (int*)blob;          // build phase only; dead before k_agg1
    __half* hwsB   = (__half*)blob;
    int*   srcs   = (int*)  alloc((size_t)NB * SCAP * 4);    // capacity layout
    (void)ws_size;  // ~65 MB used

    // ---- build (2 passes over edges; no per-edge global atomics) ----
    k_init<<<1, NB, 0, stream>>>(gcur, scal);
    k_bin<<<nblkBin, BINTH, 0, stream>>>(row, col, gcur, packed, E);
    k_place<<<nbuck, BLK, 0, stream>>>(packed, gcur, x, degi, offs, dinv, xs, srcs, n);

    // ---- GCN layers ----
    k_agg1<<<nblk64, BLK, 0, stream>>>(xs, offs, degi, srcs, dinv, b1, W1, W2, hwsB, n);
    k_agg2<<<nblk64, BLK, 0, stream>>>(hwsB, offs, degi, srcs, dinv, b2, W3, hws3, pool, n);
    k_agg3<<<nblk128, BLK, 0, stream>>>(hws3, offs, degi, srcs, dinv, b3, choices, cbuf, bmax, bsum, n);

    // ---- softmax combine fused into final ----
    k_final<<<nblkN, BLK, 0, stream>>>(cbuf, choices, bmax, bsum, pool, fcw, fcb, out, nblk128, n);
}